// Round 5
// baseline (4369.997 us; speedup 1.0000x reference)
//
#include <hip/hip_runtime.h>
#include <cfloat>

// Fixed benchmark shape.
#define BATCH     32
#define NPTS      4096
#define CDIM      256
#define KCLUST    16
#define CHUNKS    8
#define PPC       512        // points per chunk
#define TPTS      256        // points per team in phase 2 (PPC / 2 teams)
#define MAX_ITERS 20
#define TOL_F     1e-6f

// ---------------------------------------------------------------------------
// init: c0[b][k][:] = x[b][init_idx[k]][:]; zero err/ticket/conv state.
// ---------------------------------------------------------------------------
__global__ __launch_bounds__(256) void kmeans_init(
    const float* __restrict__ x, const int* __restrict__ init_idx,
    float* __restrict__ c,
    unsigned* __restrict__ errs, unsigned* __restrict__ tickets,
    unsigned* __restrict__ conv)
{
    const int b = blockIdx.x / KCLUST, k = blockIdx.x % KCLUST;
    const int t = threadIdx.x;
    const int src = init_idx[k];
    c[((size_t)b * KCLUST + k) * CDIM + t] = x[((size_t)b * NPTS + src) * CDIM + t];

    if (blockIdx.x == 0) {
        if (t < MAX_ITERS) errs[t] = 0u;
        if (t >= 64 && t < 64 + MAX_ITERS) tickets[t - 64] = 0u;
        if (t == 128) *conv = 0u;
    }
}

// ---------------------------------------------------------------------------
// assign: grid BATCH*CHUNKS (=256) blocks x 512 threads.
// Phase 0: cnorm[k] in fp64 (near-exact; order-independent at f32 visibility).
// Phase 1: thread = point. dot[n,k] accumulated in fp64 (f32->f64 cvt + fma is
//          EXACT per term). d = cn - 2*dot in fp64 -> argmin is the argmin of
//          exact distances except for ~2^-50-level ties (never, in practice).
//          Centroid reads are block-uniform -> s_load through scalar cache.
// Phase 2: thread = (team, channel). Each team serially accumulates its 256
//          points (fp64, via constant-index switch so accs stay in VGPRs);
//          team 1 stages f32 partials in LDS; team 0 combines in fixed order
//          and writes one f32 partial per (k,ch,chunk). Fully deterministic.
// ---------------------------------------------------------------------------
__global__ __launch_bounds__(512) void kmeans_assign(
    const float* __restrict__ x, const float* __restrict__ c,
    float* __restrict__ partial, int* __restrict__ pcnt,
    const unsigned* __restrict__ conv)
{
    if (*conv) return;
    const int b     = blockIdx.x / CHUNKS;
    const int chunk = blockIdx.x % CHUNKS;
    const int tid   = threadIdx.x;

    __shared__ double s_cn[KCLUST];
    __shared__ int    s_idx[PPC];
    __shared__ int    s_cnt[KCLUST];
    __shared__ float  s_part[KCLUST][CDIM];   // team-1 partials (16 KB)

    if (tid < KCLUST) {
        s_cnt[tid] = 0;
        const float* __restrict__ cr = c + ((size_t)b * KCLUST + tid) * CDIM;
        double a = 0.0;
        for (int j = 0; j < CDIM; ++j) { const double v = (double)cr[j]; a = fma(v, v, a); }
        s_cn[tid] = a;
    }
    __syncthreads();

    // ---- phase 1: one point per thread ----
    const int n = chunk * PPC + tid;
    const float4* __restrict__ xr = (const float4*)(x + ((size_t)b * NPTS + n) * CDIM);
    const float4* __restrict__ cb = (const float4*)(c + (size_t)b * KCLUST * CDIM);

    double dot[KCLUST];
#pragma unroll
    for (int k = 0; k < KCLUST; ++k) dot[k] = 0.0;

    for (int q = 0; q < CDIM / 4; ++q) {
        const float4 xv = xr[q];
        const double x0 = (double)xv.x, x1 = (double)xv.y;
        const double x2 = (double)xv.z, x3 = (double)xv.w;
#pragma unroll
        for (int k = 0; k < KCLUST; ++k) {
            const float4 cv = cb[k * (CDIM / 4) + q];   // uniform addr -> s_load
            double d = dot[k];
            d = fma(x0, (double)cv.x, d);   // each term exact (24b x 24b in 53b)
            d = fma(x1, (double)cv.y, d);
            d = fma(x2, (double)cv.z, d);
            d = fma(x3, (double)cv.w, d);
            dot[k] = d;
        }
    }

    double best = DBL_MAX;
    int   bi = 0;
#pragma unroll
    for (int k = 0; k < KCLUST; ++k) {
        const double dk = s_cn[k] - 2.0 * dot[k];
        if (dk < best) { best = dk; bi = k; }   // strict < = first-index tie rule
    }
    s_idx[tid] = bi;
    atomicAdd(&s_cnt[bi], 1);                   // int: deterministic value
    __syncthreads();

    // ---- phase 2: team = tid>>8 (0/1), channel = tid&255 ----
    const int team = tid >> 8;
    const int ch   = tid & 255;
    const float* __restrict__ xb =
        x + ((size_t)b * NPTS + chunk * PPC + team * TPTS) * CDIM + ch;
    const int* __restrict__ ip = s_idx + team * TPTS;

    double acc[KCLUST];
#pragma unroll
    for (int k = 0; k < KCLUST; ++k) acc[k] = 0.0;

#pragma unroll 8
    for (int p = 0; p < TPTS; ++p) {
        const int    k = ip[p];                        // uniform -> scalar path
        const double v = (double)xb[(size_t)p * CDIM]; // coalesced 256x4B
        switch (k) {                                   // constant idx -> VGPRs
            case 0:  acc[0]  += v; break;
            case 1:  acc[1]  += v; break;
            case 2:  acc[2]  += v; break;
            case 3:  acc[3]  += v; break;
            case 4:  acc[4]  += v; break;
            case 5:  acc[5]  += v; break;
            case 6:  acc[6]  += v; break;
            case 7:  acc[7]  += v; break;
            case 8:  acc[8]  += v; break;
            case 9:  acc[9]  += v; break;
            case 10: acc[10] += v; break;
            case 11: acc[11] += v; break;
            case 12: acc[12] += v; break;
            case 13: acc[13] += v; break;
            case 14: acc[14] += v; break;
            default: acc[15] += v; break;
        }
    }

    if (team == 1) {
#pragma unroll
        for (int k = 0; k < KCLUST; ++k) s_part[k][ch] = (float)acc[k];
    }
    __syncthreads();
    if (team == 0) {
#pragma unroll
        for (int k = 0; k < KCLUST; ++k) {
            const double tot = acc[k] + (double)s_part[k][ch];   // fixed order
            partial[(((size_t)b * KCLUST + k) * CDIM + ch) * CHUNKS + chunk] = (float)tot;
        }
    }
    if (tid < KCLUST) pcnt[(b * CHUNKS + chunk) * KCLUST + tid] = s_cnt[tid];
}

// ---------------------------------------------------------------------------
// update: grid BATCH*KCLUST x 256 threads (thread = channel).
// Fixed-order fp64 combine of 8 chunk partials + int counts -> new centroid
// (single f32 rounding), max|dc| via bit-pattern atomicMax (order-independent),
// last-finishing block folds the convergence check.
// ---------------------------------------------------------------------------
__global__ __launch_bounds__(256) void kmeans_update(
    float* __restrict__ c, const float* __restrict__ partial,
    const int* __restrict__ pcnt,
    unsigned* __restrict__ errp, unsigned* __restrict__ ticket,
    unsigned* __restrict__ conv)
{
    if (*conv) return;
    const int b = blockIdx.x / KCLUST, k = blockIdx.x % KCLUST;
    const int ch = threadIdx.x;

    int cnt = 0;
#pragma unroll
    for (int q = 0; q < CHUNKS; ++q) cnt += pcnt[(b * CHUNKS + q) * KCLUST + k];

    double s = 0.0;
    const float* __restrict__ pp = partial + (((size_t)b * KCLUST + k) * CDIM + ch) * CHUNKS;
#pragma unroll
    for (int q = 0; q < CHUNKS; ++q) s += (double)pp[q];

    const size_t ci   = ((size_t)b * KCLUST + k) * CDIM + ch;
    const float  oldv = c[ci];
    const float  newv = (cnt == 0) ? oldv : (float)(s / (double)cnt);
    const float  diff = fabsf(oldv - newv);
    c[ci] = newv;

    __shared__ float r[256];
    r[ch] = diff;
    __syncthreads();
    for (int off = 128; off > 0; off >>= 1) {
        if (ch < off) r[ch] = fmaxf(r[ch], r[ch + off]);
        __syncthreads();
    }
    if (ch == 0) {
        atomicMax(errp, __float_as_uint(r[0]));   // >=0: bits order-preserving
        __threadfence();
        const unsigned done = atomicAdd(ticket, 1u);
        if (done == (unsigned)(BATCH * KCLUST - 1)) {
            const unsigned bits = atomicMax(errp, 0u);   // atomic read of final max
            if (__uint_as_float(bits) < TOL_F) *conv = 1u;
        }
    }
}

// ---------------------------------------------------------------------------
extern "C" void kernel_launch(void* const* d_in, const int* in_sizes, int n_in,
                              void* d_out, int out_size, void* d_ws, size_t ws_size,
                              hipStream_t stream)
{
    const float* x        = (const float*)d_in[0];
    const int*   init_idx = (const int*)d_in[1];   // integers arrive as int32
    float* c = (float*)d_out;                      // centroids (B*K*C floats)

    // Workspace: partial f32 [B][K][C][CHUNKS] = 4 MiB, pcnt 16 KiB, flags.
    float*    partial = (float*)d_ws;
    int*      pcnt    = (int*)(partial + (size_t)BATCH * KCLUST * CDIM * CHUNKS);
    unsigned* errs    = (unsigned*)(pcnt + BATCH * CHUNKS * KCLUST);  // MAX_ITERS
    unsigned* tickets = errs + MAX_ITERS;                             // MAX_ITERS
    unsigned* conv    = tickets + MAX_ITERS;                          // 1

    kmeans_init<<<BATCH * KCLUST, 256, 0, stream>>>(x, init_idx, c, errs, tickets, conv);

    for (int i = 0; i < MAX_ITERS; ++i) {
        kmeans_assign<<<BATCH * CHUNKS, 512, 0, stream>>>(x, c, partial, pcnt, conv);
        kmeans_update<<<BATCH * KCLUST, 256, 0, stream>>>(c, partial, pcnt,
                                                          &errs[i], &tickets[i], conv);
    }
}

// Round 6
// 4299.826 us; speedup vs baseline: 1.0163x; 1.0163x over previous
//
#include <hip/hip_runtime.h>
#include <cfloat>

// Fixed benchmark shape.
#define BATCH     32
#define NPTS      4096
#define CDIM      256
#define KCLUST    16
#define CHUNKS    8
#define PPC       512        // points per chunk
#define TPTS      256        // points per team in phase 2 (PPC / 2 teams)
#define MAX_ITERS 20
#define TOL_F     1e-6f

// ---------------------------------------------------------------------------
// init: c0[b][k][:] = x[b][init_idx[k]][:]; zero err/ticket/conv state.
// ---------------------------------------------------------------------------
__global__ __launch_bounds__(256) void kmeans_init(
    const float* __restrict__ x, const int* __restrict__ init_idx,
    float* __restrict__ c,
    unsigned* __restrict__ errs, unsigned* __restrict__ tickets,
    unsigned* __restrict__ conv)
{
    const int b = blockIdx.x / KCLUST, k = blockIdx.x % KCLUST;
    const int t = threadIdx.x;
    const int src = init_idx[k];
    c[((size_t)b * KCLUST + k) * CDIM + t] = x[((size_t)b * NPTS + src) * CDIM + t];

    if (blockIdx.x == 0) {
        if (t < MAX_ITERS) errs[t] = 0u;
        if (t >= 64 && t < 64 + MAX_ITERS) tickets[t - 64] = 0u;
        if (t == 128) *conv = 0u;
    }
}

// ---------------------------------------------------------------------------
// assign: grid BATCH*CHUNKS (=256) blocks x 512 threads.
// Phase 0: cnorm[k] in fp64 (near-exact -> argmin offsets stable).
// Phase 1: thread = point. dot[n,k] in fp32 using the round-2-VALIDATED
//          expression (float4 products, left-to-right adds, default
//          fp-contract): deterministic, absmax ~1e-4 empirically.
//          Centroid reads are block-uniform -> s_load via scalar cache.
// Phase 2: thread = (team, channel). fp64 serial accumulate via constant-index
//          switch (VGPR-resident, rule #20); team combine in fixed order.
//          Bit-identical to the round-5 passing run.
// ---------------------------------------------------------------------------
__global__ __launch_bounds__(512) void kmeans_assign(
    const float* __restrict__ x, const float* __restrict__ c,
    float* __restrict__ partial, int* __restrict__ pcnt,
    const unsigned* __restrict__ conv)
{
    if (*conv) return;
    const int b     = blockIdx.x / CHUNKS;
    const int chunk = blockIdx.x % CHUNKS;
    const int tid   = threadIdx.x;

    __shared__ double s_cn[KCLUST];
    __shared__ int    s_idx[PPC];
    __shared__ int    s_cnt[KCLUST];
    __shared__ float  s_part[KCLUST][CDIM];   // team-1 partials (16 KB)

    if (tid < KCLUST) {
        s_cnt[tid] = 0;
        const float* __restrict__ cr = c + ((size_t)b * KCLUST + tid) * CDIM;
        double a = 0.0;
        for (int j = 0; j < CDIM; ++j) { const double v = (double)cr[j]; a = fma(v, v, a); }
        s_cn[tid] = a;
    }
    __syncthreads();

    // ---- phase 1: one point per thread, fp32 dots ----
    const int n = chunk * PPC + tid;
    const float4* __restrict__ xr = (const float4*)(x + ((size_t)b * NPTS + n) * CDIM);
    const float4* __restrict__ cb = (const float4*)(c + (size_t)b * KCLUST * CDIM);

    float dot[KCLUST];
#pragma unroll
    for (int k = 0; k < KCLUST; ++k) dot[k] = 0.0f;

#pragma unroll 4
    for (int q = 0; q < CDIM / 4; ++q) {
        const float4 xv = xr[q];
#pragma unroll
        for (int k = 0; k < KCLUST; ++k) {
            const float4 cv = cb[k * (CDIM / 4) + q];   // uniform addr -> s_load
            // Round-2-validated rounding order: products summed left-to-right,
            // then added into the accumulator (deterministic).
            dot[k] += xv.x * cv.x + xv.y * cv.y + xv.z * cv.z + xv.w * cv.w;
        }
    }

    float best = FLT_MAX;
    int   bi = 0;
#pragma unroll
    for (int k = 0; k < KCLUST; ++k) {
        const float dk = (float)s_cn[k] - 2.0f * dot[k];
        if (dk < best) { best = dk; bi = k; }   // strict < = first-index tie rule
    }
    s_idx[tid] = bi;
    atomicAdd(&s_cnt[bi], 1);                   // int: deterministic value
    __syncthreads();

    // ---- phase 2: team = tid>>8 (0/1), channel = tid&255 (fp64, fixed order) ----
    const int team = tid >> 8;
    const int ch   = tid & 255;
    const float* __restrict__ xb =
        x + ((size_t)b * NPTS + chunk * PPC + team * TPTS) * CDIM + ch;
    const int* __restrict__ ip = s_idx + team * TPTS;

    double acc[KCLUST];
#pragma unroll
    for (int k = 0; k < KCLUST; ++k) acc[k] = 0.0;

#pragma unroll 8
    for (int p = 0; p < TPTS; ++p) {
        const int    k = ip[p];                        // uniform -> scalar path
        const double v = (double)xb[(size_t)p * CDIM]; // coalesced 256x4B
        switch (k) {                                   // constant idx -> VGPRs
            case 0:  acc[0]  += v; break;
            case 1:  acc[1]  += v; break;
            case 2:  acc[2]  += v; break;
            case 3:  acc[3]  += v; break;
            case 4:  acc[4]  += v; break;
            case 5:  acc[5]  += v; break;
            case 6:  acc[6]  += v; break;
            case 7:  acc[7]  += v; break;
            case 8:  acc[8]  += v; break;
            case 9:  acc[9]  += v; break;
            case 10: acc[10] += v; break;
            case 11: acc[11] += v; break;
            case 12: acc[12] += v; break;
            case 13: acc[13] += v; break;
            case 14: acc[14] += v; break;
            default: acc[15] += v; break;
        }
    }

    if (team == 1) {
#pragma unroll
        for (int k = 0; k < KCLUST; ++k) s_part[k][ch] = (float)acc[k];
    }
    __syncthreads();
    if (team == 0) {
#pragma unroll
        for (int k = 0; k < KCLUST; ++k) {
            const double tot = acc[k] + (double)s_part[k][ch];   // fixed order
            partial[(((size_t)b * KCLUST + k) * CDIM + ch) * CHUNKS + chunk] = (float)tot;
        }
    }
    if (tid < KCLUST) pcnt[(b * CHUNKS + chunk) * KCLUST + tid] = s_cnt[tid];
}

// ---------------------------------------------------------------------------
// update: grid BATCH*KCLUST x 256 threads (thread = channel).
// Fixed-order fp64 combine of 8 chunk partials + int counts -> new centroid
// (single f32 rounding), max|dc| via bit-pattern atomicMax, last-finishing
// block folds the convergence check.
// ---------------------------------------------------------------------------
__global__ __launch_bounds__(256) void kmeans_update(
    float* __restrict__ c, const float* __restrict__ partial,
    const int* __restrict__ pcnt,
    unsigned* __restrict__ errp, unsigned* __restrict__ ticket,
    unsigned* __restrict__ conv)
{
    if (*conv) return;
    const int b = blockIdx.x / KCLUST, k = blockIdx.x % KCLUST;
    const int ch = threadIdx.x;

    int cnt = 0;
#pragma unroll
    for (int q = 0; q < CHUNKS; ++q) cnt += pcnt[(b * CHUNKS + q) * KCLUST + k];

    double s = 0.0;
    const float* __restrict__ pp = partial + (((size_t)b * KCLUST + k) * CDIM + ch) * CHUNKS;
#pragma unroll
    for (int q = 0; q < CHUNKS; ++q) s += (double)pp[q];

    const size_t ci   = ((size_t)b * KCLUST + k) * CDIM + ch;
    const float  oldv = c[ci];
    const float  newv = (cnt == 0) ? oldv : (float)(s / (double)cnt);
    const float  diff = fabsf(oldv - newv);
    c[ci] = newv;

    __shared__ float r[256];
    r[ch] = diff;
    __syncthreads();
    for (int off = 128; off > 0; off >>= 1) {
        if (ch < off) r[ch] = fmaxf(r[ch], r[ch + off]);
        __syncthreads();
    }
    if (ch == 0) {
        atomicMax(errp, __float_as_uint(r[0]));   // >=0: bits order-preserving
        __threadfence();
        const unsigned done = atomicAdd(ticket, 1u);
        if (done == (unsigned)(BATCH * KCLUST - 1)) {
            const unsigned bits = atomicMax(errp, 0u);   // atomic read of final max
            if (__uint_as_float(bits) < TOL_F) *conv = 1u;
        }
    }
}

// ---------------------------------------------------------------------------
extern "C" void kernel_launch(void* const* d_in, const int* in_sizes, int n_in,
                              void* d_out, int out_size, void* d_ws, size_t ws_size,
                              hipStream_t stream)
{
    const float* x        = (const float*)d_in[0];
    const int*   init_idx = (const int*)d_in[1];   // integers arrive as int32
    float* c = (float*)d_out;                      // centroids (B*K*C floats)

    // Workspace: partial f32 [B][K][C][CHUNKS] = 4 MiB, pcnt 16 KiB, flags.
    float*    partial = (float*)d_ws;
    int*      pcnt    = (int*)(partial + (size_t)BATCH * KCLUST * CDIM * CHUNKS);
    unsigned* errs    = (unsigned*)(pcnt + BATCH * CHUNKS * KCLUST);  // MAX_ITERS
    unsigned* tickets = errs + MAX_ITERS;                             // MAX_ITERS
    unsigned* conv    = tickets + MAX_ITERS;                          // 1

    kmeans_init<<<BATCH * KCLUST, 256, 0, stream>>>(x, init_idx, c, errs, tickets, conv);

    for (int i = 0; i < MAX_ITERS; ++i) {
        kmeans_assign<<<BATCH * CHUNKS, 512, 0, stream>>>(x, c, partial, pcnt, conv);
        kmeans_update<<<BATCH * KCLUST, 256, 0, stream>>>(c, partial, pcnt,
                                                          &errs[i], &tickets[i], conv);
    }
}

// Round 9
// 2668.684 us; speedup vs baseline: 1.6375x; 1.6112x over previous
//
#include <hip/hip_runtime.h>
#include <cfloat>

// Fixed benchmark shape.
#define BATCH     32
#define NPTS      4096
#define CDIM      256
#define KCLUST    16
#define ACH       16         // assign: chunks per batch (256 points each)
#define MAX_ITERS 20
#define TOL_F     1e-6f

#define KLIST(F) F(0) F(1) F(2) F(3) F(4) F(5) F(6) F(7) \
                 F(8) F(9) F(10) F(11) F(12) F(13) F(14) F(15)

// ---------------------------------------------------------------------------
// init: c0 = x[init_idx] (f32 + f64 copies), cnorm64, zero flags.
// ---------------------------------------------------------------------------
__global__ __launch_bounds__(256) void kmeans_init(
    const float* __restrict__ x, const int* __restrict__ init_idx,
    float* __restrict__ c, double* __restrict__ c64, double* __restrict__ cn64,
    unsigned* __restrict__ errs, unsigned* __restrict__ tickets,
    unsigned* __restrict__ conv)
{
    const int b = blockIdx.x / KCLUST, k = blockIdx.x % KCLUST;
    const int t = threadIdx.x;
    const int src = init_idx[k];
    const float v = x[((size_t)b * NPTS + src) * CDIM + t];
    const size_t ci = ((size_t)b * KCLUST + k) * CDIM + t;
    c[ci]   = v;
    c64[ci] = (double)v;

    __shared__ double red[256];
    red[t] = (double)v * (double)v;
    __syncthreads();
    for (int off = 128; off > 0; off >>= 1) {
        if (t < off) red[t] += red[t + off];
        __syncthreads();
    }
    if (t == 0) cn64[b * KCLUST + k] = red[0];

    if (blockIdx.x == 0) {
        if (t < MAX_ITERS) errs[t] = 0u;
        if (t >= 64 && t < 64 + MAX_ITERS) tickets[t - 64] = 0u;
        if (t == 128) *conv = 0u;
    }
}

// ---------------------------------------------------------------------------
// kassign: grid BATCH*ACH (=512) x 256. Thread = point. Pure fp64 distance
// argmin (order-robust: argmin == exact argmin; every downstream restructure
// is numerically safe). Centroids read from pre-converted c64 via block-
// uniform addresses (scalar cache); no per-term converts in the inner loop.
// ---------------------------------------------------------------------------
__global__ __launch_bounds__(256) void kassign(
    const float* __restrict__ x, const double* __restrict__ c64,
    const double* __restrict__ cn64, unsigned char* __restrict__ idx,
    const unsigned* __restrict__ conv)
{
    if (*conv) return;
    const int b     = blockIdx.x / ACH;
    const int chunk = blockIdx.x % ACH;
    const int tid   = threadIdx.x;

    __shared__ double s_cn[KCLUST];
    if (tid < KCLUST) s_cn[tid] = cn64[b * KCLUST + tid];
    __syncthreads();

    const int n = chunk * 256 + tid;
    const float4*  __restrict__ xr = (const float4*)(x + ((size_t)b * NPTS + n) * CDIM);
    const double2* __restrict__ cb = (const double2*)(c64 + (size_t)b * KCLUST * CDIM);

    double dot[KCLUST];
#pragma unroll
    for (int k = 0; k < KCLUST; ++k) dot[k] = 0.0;

#pragma unroll 4
    for (int q = 0; q < CDIM / 4; ++q) {
        const float4 xv = xr[q];
        const double x0 = (double)xv.x, x1 = (double)xv.y;
        const double x2 = (double)xv.z, x3 = (double)xv.w;
#pragma unroll
        for (int k = 0; k < KCLUST; ++k) {
            const double2 cA = cb[k * (CDIM / 2) + 2 * q];      // uniform -> s_load
            const double2 cB = cb[k * (CDIM / 2) + 2 * q + 1];
            double d = dot[k];
            d = fma(x0, cA.x, d);
            d = fma(x1, cA.y, d);
            d = fma(x2, cB.x, d);
            d = fma(x3, cB.y, d);
            dot[k] = d;
        }
    }

    double best = DBL_MAX;
    int   bi = 0;
#pragma unroll
    for (int k = 0; k < KCLUST; ++k) {
        const double dk = s_cn[k] - 2.0 * dot[k];
        if (dk < best) { best = dk; bi = k; }   // strict < = first-index tie rule
    }
    idx[(size_t)b * NPTS + n] = (unsigned char)bi;
}

// ---------------------------------------------------------------------------
// kaccum<NCH>: grid BATCH*NCH x 1024 (4 teams x 256 ch). Each team serially
// accumulates its PPB/4 points in fp64 (named regs, rule #20); cluster id
// forced scalar via readfirstlane -> uniform scalar branch (no exec-mask
// divergence). Teams 1-3 stage f32 partials+counts in LDS; team 0 combines
// in fixed order -> deterministic. (fp64 argmin makes rounding detail free.)
// ---------------------------------------------------------------------------
template <int NCH>
__global__ __launch_bounds__(1024) void kaccum(
    const float* __restrict__ x, const unsigned char* __restrict__ idx,
    float* __restrict__ partial, int* __restrict__ pcnt,
    const unsigned* __restrict__ conv)
{
    if (*conv) return;
    constexpr int PPB = NPTS / NCH;
    constexpr int TP  = PPB / 4;
    const int b   = blockIdx.x / NCH;
    const int qc  = blockIdx.x % NCH;
    const int tid = threadIdx.x;
    const int team = tid >> 8, ch = tid & 255;

    __shared__ unsigned char s_k[PPB];
    __shared__ float s_part[3][KCLUST][CDIM];
    __shared__ int   s_cnt[3][KCLUST];

    for (int i = tid; i < PPB; i += 1024)
        s_k[i] = idx[(size_t)b * NPTS + qc * PPB + i];
    __syncthreads();

    const float* __restrict__ xb =
        x + ((size_t)b * NPTS + qc * PPB + team * TP) * CDIM + ch;
    const unsigned char* __restrict__ kp = s_k + team * TP;

#define DECL(i) double a##i = 0.0; int n##i = 0;
    KLIST(DECL)
#undef DECL

#pragma unroll 4
    for (int p = 0; p < TP; ++p) {
        const double dv = (double)xb[(size_t)p * CDIM];            // coalesced
        const int k = __builtin_amdgcn_readfirstlane((int)kp[p]);  // force scalar
        switch (k) {
#define CASE(i) case i: a##i += dv; ++n##i; break;
            KLIST(CASE)
#undef CASE
        }
    }

    if (team > 0) {
        float* __restrict__ sp = &s_part[team - 1][0][ch];
#define TWRITE(i) sp[i * CDIM] = (float)a##i;
        KLIST(TWRITE)
#undef TWRITE
        if (ch == 0) {
            int* __restrict__ sc = s_cnt[team - 1];
#define CWRITE(i) sc[i] = n##i;
            KLIST(CWRITE)
#undef CWRITE
        }
    }
    __syncthreads();

    if (team == 0) {
        float* __restrict__ po =
            partial + (((size_t)b * NCH + qc) * KCLUST) * CDIM + ch;
        const float* __restrict__ sp0 = &s_part[0][0][ch];
        const float* __restrict__ sp1 = &s_part[1][0][ch];
        const float* __restrict__ sp2 = &s_part[2][0][ch];
#define COMB(i) po[i * CDIM] = (float)(a##i + (double)sp0[i * CDIM] \
                                     + (double)sp1[i * CDIM] + (double)sp2[i * CDIM]);
        KLIST(COMB)
#undef COMB
        if (ch == 0) {
            int* __restrict__ pc = pcnt + ((size_t)b * NCH + qc) * KCLUST;
#define PCW(i) pc[i] = n##i + s_cnt[0][i] + s_cnt[1][i] + s_cnt[2][i];
            KLIST(PCW)
#undef PCW
        }
    }
}

// ---------------------------------------------------------------------------
// kupdate<NCH>: grid BATCH*KCLUST x 256 (thread = channel). Fixed-order fp64
// combine of NCH partials + counts -> new centroid (f32 + f64 copies),
// cnorm64, max|dc| via bit-pattern atomicMax, last block folds convergence.
// ---------------------------------------------------------------------------
template <int NCH>
__global__ __launch_bounds__(256) void kupdate(
    float* __restrict__ c, double* __restrict__ c64, double* __restrict__ cn64,
    const float* __restrict__ partial, const int* __restrict__ pcnt,
    unsigned* __restrict__ errp, unsigned* __restrict__ ticket,
    unsigned* __restrict__ conv)
{
    if (*conv) return;
    const int b = blockIdx.x / KCLUST, k = blockIdx.x % KCLUST;
    const int ch = threadIdx.x;

    int cnt = 0;
#pragma unroll
    for (int q = 0; q < NCH; ++q)
        cnt += pcnt[((size_t)b * NCH + q) * KCLUST + k];          // uniform

    double s = 0.0;
#pragma unroll
    for (int q = 0; q < NCH; ++q)
        s += (double)partial[(((size_t)b * NCH + q) * KCLUST + k) * CDIM + ch];

    const size_t ci   = ((size_t)b * KCLUST + k) * CDIM + ch;
    const float  oldv = c[ci];
    const float  newv = (cnt == 0) ? oldv : (float)(s / (double)cnt);
    const float  diff = fabsf(oldv - newv);
    c[ci]   = newv;
    c64[ci] = (double)newv;

    __shared__ double rs[256];
    __shared__ float  rm[256];
    rs[ch] = (double)newv * (double)newv;
    rm[ch] = diff;
    __syncthreads();
    for (int off = 128; off > 0; off >>= 1) {
        if (ch < off) { rs[ch] += rs[ch + off]; rm[ch] = fmaxf(rm[ch], rm[ch + off]); }
        __syncthreads();
    }
    if (ch == 0) {
        cn64[b * KCLUST + k] = rs[0];
        atomicMax(errp, __float_as_uint(rm[0]));   // >=0: bits order-preserving
        __threadfence();
        const unsigned done = atomicAdd(ticket, 1u);
        if (done == (unsigned)(BATCH * KCLUST - 1)) {
            const unsigned bits = atomicMax(errp, 0u);
            if (__uint_as_float(bits) < TOL_F) *conv = 1u;
        }
    }
}

// ---------------------------------------------------------------------------
extern "C" void kernel_launch(void* const* d_in, const int* in_sizes, int n_in,
                              void* d_out, int out_size, void* d_ws, size_t ws_size,
                              hipStream_t stream)
{
    const float* x        = (const float*)d_in[0];
    const int*   init_idx = (const int*)d_in[1];
    float* c = (float*)d_out;                      // centroids (B*K*C floats)

    // ws layout: c64 (1MB) | cn64 (4KB) | partial (4MB/2MB) | pcnt | idx | flags
    char* w = (char*)d_ws;
    double* c64  = (double*)w;  w += (size_t)BATCH * KCLUST * CDIM * 8;
    double* cn64 = (double*)w;  w += (size_t)BATCH * KCLUST * 8;
    const size_t fixed = (size_t)(w - (char*)d_ws);
    const size_t need8 = fixed
        + (size_t)BATCH * 8 * KCLUST * CDIM * 4 + (size_t)BATCH * 8 * KCLUST * 4
        + (size_t)BATCH * NPTS + (2 * MAX_ITERS + 1) * 4;
    const bool big = (ws_size >= need8);           // constant per process: graph-safe
    const int  nch = big ? 8 : 4;

    float*         partial = (float*)w;  w += (size_t)BATCH * nch * KCLUST * CDIM * 4;
    int*           pcnt    = (int*)w;    w += (size_t)BATCH * nch * KCLUST * 4;
    unsigned char* idx     = (unsigned char*)w;  w += (size_t)BATCH * NPTS;
    unsigned*      errs    = (unsigned*)w;
    unsigned*      tickets = errs + MAX_ITERS;
    unsigned*      conv    = tickets + MAX_ITERS;

    kmeans_init<<<BATCH * KCLUST, 256, 0, stream>>>(x, init_idx, c, c64, cn64,
                                                    errs, tickets, conv);

    for (int i = 0; i < MAX_ITERS; ++i) {
        kassign<<<BATCH * ACH, 256, 0, stream>>>(x, c64, cn64, idx, conv);
        if (big) {
            kaccum<8><<<BATCH * 8, 1024, 0, stream>>>(x, idx, partial, pcnt, conv);
            kupdate<8><<<BATCH * KCLUST, 256, 0, stream>>>(c, c64, cn64, partial, pcnt,
                                                           &errs[i], &tickets[i], conv);
        } else {
            kaccum<4><<<BATCH * 4, 1024, 0, stream>>>(x, idx, partial, pcnt, conv);
            kupdate<4><<<BATCH * KCLUST, 256, 0, stream>>>(c, c64, cn64, partial, pcnt,
                                                           &errs[i], &tickets[i], conv);
        }
    }
}